// Round 1
// 294.810 us; speedup vs baseline: 1.3234x; 1.3234x over previous
//
#include <hip/hip_runtime.h>

#define B_    2
#define S_    2048
#define H_    32
#define KVH_  8
#define D_    128
#define QB    128
#define KB    64
#define NT_   (S_ / KB)
#define NREP  (H_ / KVH_)
#define SCALE 0.08838834764831845f  // 128^-0.5

typedef short  short8 __attribute__((ext_vector_type(8)));
typedef float  f32x4  __attribute__((ext_vector_type(4)));

__device__ inline unsigned short f2bf(float f) {
    unsigned int u = __float_as_uint(f);
    u += 0x7fffu + ((u >> 16) & 1u);
    return (unsigned short)(u >> 16);
}

// ---- prepass: build MFMA-fragment-ordered bf16 K and V (verified round 5) ----
// kfb[(bkvh*NT+kt)*16 + (c*4+nt)][lane]  : K[key=kt*64+nt*16+m16][d=c*32+quad*8+j]
// vfb[(bkvh*NT+kt)*16 + (c2*8+dn)][lane] : V[key=kt*64+c2*32+quad*8+j][d=dn*16+m16]
__global__ void prep_kernel(const float* __restrict__ k, const float* __restrict__ v,
                            unsigned short* __restrict__ kfb,
                            unsigned short* __restrict__ vfb) {
    __shared__ unsigned short Kt[64][136];
    __shared__ unsigned short Vt[64][136];
    const int t = threadIdx.x;
    const int kt = blockIdx.x, bkvh = blockIdx.y;
    const int b = bkvh >> 3, kvh = bkvh & 7;
    const size_t rs = KVH_ * D_;
    const float* ks = k + ((size_t)(b * S_ + kt * 64)) * rs + kvh * D_;
    const float* vs = v + ((size_t)(b * S_ + kt * 64)) * rs + kvh * D_;
    #pragma unroll
    for (int i = 0; i < 8; ++i) {
        const int row = (t >> 5) + i * 8;
        const int col = (t & 31) * 4;
        const float4 a = *(const float4*)(ks + (size_t)row * rs + col);
        const float4 c = *(const float4*)(vs + (size_t)row * rs + col);
        ushort4 wa, wc;
        wa.x = f2bf(a.x); wa.y = f2bf(a.y); wa.z = f2bf(a.z); wa.w = f2bf(a.w);
        wc.x = f2bf(c.x); wc.y = f2bf(c.y); wc.z = f2bf(c.z); wc.w = f2bf(c.w);
        *(ushort4*)&Kt[row][col] = wa;
        *(ushort4*)&Vt[row][col] = wc;
    }
    __syncthreads();
    const int lane = t & 63, m16 = lane & 15, quad = lane >> 4;
    unsigned short* kout = kfb + (size_t)(bkvh * NT_ + kt) * 16 * 512;
    unsigned short* vout = vfb + (size_t)(bkvh * NT_ + kt) * 16 * 512;
    #pragma unroll
    for (int i = 0; i < 4; ++i) {
        const int g = (t >> 6) * 4 + i;          // 0..15
        const int c = g >> 2, nt = g & 3;
        const short8 kk = *(const short8*)&Kt[nt * 16 + m16][c * 32 + quad * 8];
        *(short8*)(kout + g * 512 + lane * 8) = kk;
        const int c2 = g >> 3, dn = g & 7;
        short8 vv;
        #pragma unroll
        for (int j = 0; j < 8; ++j)
            vv[j] = (short)Vt[c2 * 32 + quad * 8 + j][dn * 16 + m16];
        *(short8*)(vout + g * 512 + lane * 8) = vv;
    }
}

// ---- fa7: double-buffered LDS K/V staging via global_load_lds + causal pairing ----
// LDS map (bytes): buf0 K[0,16K) V[16K,32K) | buf1 K[32K,48K) V[48K,64K)
//                  Psh [64K, 64K+9216)  (64 rows x 72 shorts, per-rb ping-pong)
//                  epilogue fp32 slab 4x[16][128] aliases buf0/buf1 after final barrier
#define P_STRIDE  72
#define KV_TILE_B 16384
#define BUF_B     32768
#define PSH_OFF   65536
#define SMEM_B    (PSH_OFF + 64 * P_STRIDE * 2)   // 74752 -> 2 blocks/CU

__device__ __forceinline__ void gld16(const void* g, void* l) {
    __builtin_amdgcn_global_load_lds(
        (const __attribute__((address_space(1))) unsigned int*)g,
        (__attribute__((address_space(3))) unsigned int*)l, 16, 0, 0);
}

__global__ __launch_bounds__(256, 2) void fa7_kernel(
    const float* __restrict__ q, const unsigned short* __restrict__ kfb,
    const unsigned short* __restrict__ vfb, float* __restrict__ out) {

    __shared__ __align__(16) char smem[SMEM_B];
    unsigned short* Psh = (unsigned short*)(smem + PSH_OFF);

    const int t    = threadIdx.x;
    const int wave = t >> 6;
    const int lane = t & 63;
    const int m16  = lane & 15;
    const int quad = lane >> 4;

    const int bh  = blockIdx.y;
    const int b   = bh >> 5;
    const int h   = bh & 31;
    const int kvh = h >> 2;

    const char* kB = (const char*)kfb + (size_t)(b * KVH_ + kvh) * NT_ * KV_TILE_B;
    const char* vB = (const char*)vfb + (size_t)(b * KVH_ + kvh) * NT_ * KV_TILE_B;

    // causal pairing: qtile (15-bx) then (bx) -> every block does 34 k-tile iterations
    for (int half = 0; half < 2; ++half) {
        const int qtile = half ? (int)blockIdx.x : (S_ / QB - 1 - (int)blockIdx.x);
        const int qbase = qtile * QB;
        const int ktmax = 2 * qtile + 1;   // k-tiles 0..ktmax cover keys < qbase+128

        if (half) __syncthreads();   // epilogue slab reads of half 0 done before restaging buf0

        // ---- stage tile 0 -> buf0 (async, VGPR-free; 256 thr x 16B x 4 rounds each for K,V) ----
        #pragma unroll
        for (int r = 0; r < 4; ++r) {
            gld16(kB + r * 4096 + t * 16, smem + r * 4096 + t * 16);
            gld16(vB + r * 4096 + t * 16, smem + KV_TILE_B + r * 4096 + t * 16);
        }

        // ---- Q A-fragments for both row-blocks (latency hides under the sync drain) ----
        short8 qf[2][4];
        #pragma unroll
        for (int rb = 0; rb < 2; ++rb) {
            const float* qp = q + (size_t)(b * S_ + qbase + rb * 64 + wave * 16 + m16) * (H_ * D_) + h * D_;
            #pragma unroll
            for (int c = 0; c < 4; ++c) {
                const float4 x0 = *(const float4*)(qp + c * 32 + quad * 8);
                const float4 x1 = *(const float4*)(qp + c * 32 + quad * 8 + 4);
                short8 f;
                f[0] = (short)f2bf(x0.x); f[1] = (short)f2bf(x0.y);
                f[2] = (short)f2bf(x0.z); f[3] = (short)f2bf(x0.w);
                f[4] = (short)f2bf(x1.x); f[5] = (short)f2bf(x1.y);
                f[6] = (short)f2bf(x1.z); f[7] = (short)f2bf(x1.w);
                qf[rb][c] = f;
            }
        }

        f32x4 o[2][8];
        #pragma unroll
        for (int rb = 0; rb < 2; ++rb)
            #pragma unroll
            for (int i = 0; i < 8; ++i) o[rb][i] = (f32x4){0.f, 0.f, 0.f, 0.f};
        float m_i[2][4], l_i[2][4];
        #pragma unroll
        for (int rb = 0; rb < 2; ++rb)
            #pragma unroll
            for (int r = 0; r < 4; ++r) { m_i[rb][r] = -INFINITY; l_i[rb][r] = 0.f; }

        __syncthreads();   // drains vmcnt(0): tile 0 staged and visible

        for (int ktt = 0; ktt <= ktmax; ++ktt) {
            const int kb  = ktt * KB;
            const int cur = ktt & 1;

            // ---- issue next tile's staging; flies under this tile's compute ----
            if (ktt < ktmax) {
                char* dst = smem + (cur ^ 1) * BUF_B + t * 16;
                const char* ks = kB + (size_t)(ktt + 1) * KV_TILE_B + t * 16;
                const char* vs = vB + (size_t)(ktt + 1) * KV_TILE_B + t * 16;
                #pragma unroll
                for (int r = 0; r < 4; ++r) {
                    gld16(ks + r * 4096, dst + r * 4096);
                    gld16(vs + r * 4096, dst + KV_TILE_B + r * 4096);
                }
            }
            const unsigned short* Kl = (const unsigned short*)(smem + cur * BUF_B);
            const unsigned short* Vl = Kl + KV_TILE_B / 2;

            // ---- S = Q K^T, K frags from LDS (contiguous 1KB ds_read_b128, conflict-free) ----
            f32x4 sa[2][4];
            #pragma unroll
            for (int rb = 0; rb < 2; ++rb)
                #pragma unroll
                for (int nt = 0; nt < 4; ++nt) sa[rb][nt] = (f32x4){0.f, 0.f, 0.f, 0.f};
            #pragma unroll
            for (int c = 0; c < 4; ++c) {
                short8 kf[4];
                #pragma unroll
                for (int nt = 0; nt < 4; ++nt)
                    kf[nt] = *(const short8*)(Kl + (c * 4 + nt) * 512 + lane * 8);
                #pragma unroll
                for (int nt = 0; nt < 4; ++nt) {
                    sa[0][nt] = __builtin_amdgcn_mfma_f32_16x16x32_bf16(qf[0][c], kf[nt], sa[0][nt], 0, 0, 0);
                    sa[1][nt] = __builtin_amdgcn_mfma_f32_16x16x32_bf16(qf[1][c], kf[nt], sa[1][nt], 0, 0, 0);
                }
            }

            // ---- mask + online softmax; Psh ping-pong per row-block (wave-private rows) ----
            const bool dodiag = (ktt >= 2 * qtile);
            short8 pf0[2], pf1[2];
            #pragma unroll
            for (int rb = 0; rb < 2; ++rb) {
                float p[4][4];
                #pragma unroll
                for (int nt = 0; nt < 4; ++nt) {
                    #pragma unroll
                    for (int r = 0; r < 4; ++r) {
                        float sv = sa[rb][nt][r] * SCALE;
                        if (dodiag) {
                            const int rowg = qbase + rb * 64 + wave * 16 + quad * 4 + r;
                            const int colg = kb + nt * 16 + m16;
                            if (colg > rowg) sv = -INFINITY;
                        }
                        p[nt][r] = sv;
                    }
                }
                float alpha[4];
                #pragma unroll
                for (int r = 0; r < 4; ++r) {
                    float mv = fmaxf(fmaxf(p[0][r], p[1][r]), fmaxf(p[2][r], p[3][r]));
                    mv = fmaxf(mv, __shfl_xor(mv, 1));
                    mv = fmaxf(mv, __shfl_xor(mv, 2));
                    mv = fmaxf(mv, __shfl_xor(mv, 4));
                    mv = fmaxf(mv, __shfl_xor(mv, 8));
                    const float mnew = fmaxf(m_i[rb][r], mv);
                    alpha[r] = __expf(m_i[rb][r] - mnew);
                    m_i[rb][r] = mnew;
                    float rs = 0.f;
                    #pragma unroll
                    for (int nt = 0; nt < 4; ++nt) {
                        const float e = __expf(p[nt][r] - mnew);
                        p[nt][r] = e;
                        rs += e;
                    }
                    rs += __shfl_xor(rs, 1);
                    rs += __shfl_xor(rs, 2);
                    rs += __shfl_xor(rs, 4);
                    rs += __shfl_xor(rs, 8);
                    l_i[rb][r] = l_i[rb][r] * alpha[r] + rs;
                }
                #pragma unroll
                for (int nt = 0; nt < 4; ++nt)
                    #pragma unroll
                    for (int r = 0; r < 4; ++r)
                        Psh[(wave * 16 + quad * 4 + r) * P_STRIDE + nt * 16 + m16] = f2bf(p[nt][r]);
                #pragma unroll
                for (int dn = 0; dn < 8; ++dn)
                    #pragma unroll
                    for (int r = 0; r < 4; ++r)
                        o[rb][dn][r] *= alpha[r];
                // same-wave LDS RAW: drain P writes before reading A-fragments.
                // rb=1 writes queue after rb=0 reads in the per-wave in-order LDS queue (WAR safe).
                asm volatile("s_waitcnt lgkmcnt(0)" ::: "memory");
                if (rb == 0) {
                    pf0[0] = *(const short8*)&Psh[(wave * 16 + m16) * P_STRIDE + quad * 8];
                    pf0[1] = *(const short8*)&Psh[(wave * 16 + m16) * P_STRIDE + 32 + quad * 8];
                } else {
                    pf1[0] = *(const short8*)&Psh[(wave * 16 + m16) * P_STRIDE + quad * 8];
                    pf1[1] = *(const short8*)&Psh[(wave * 16 + m16) * P_STRIDE + 32 + quad * 8];
                }
            }

            // ---- O += P V, V frags from LDS (read once, used for both row-blocks) ----
            #pragma unroll
            for (int dn = 0; dn < 8; ++dn) {
                const short8 vv = *(const short8*)(Vl + dn * 512 + lane * 8);
                o[0][dn] = __builtin_amdgcn_mfma_f32_16x16x32_bf16(pf0[0], vv, o[0][dn], 0, 0, 0);
                o[1][dn] = __builtin_amdgcn_mfma_f32_16x16x32_bf16(pf1[0], vv, o[1][dn], 0, 0, 0);
            }
            #pragma unroll
            for (int dn = 0; dn < 8; ++dn) {
                const short8 vv = *(const short8*)(Vl + (8 + dn) * 512 + lane * 8);
                o[0][dn] = __builtin_amdgcn_mfma_f32_16x16x32_bf16(pf0[1], vv, o[0][dn], 0, 0, 0);
                o[1][dn] = __builtin_amdgcn_mfma_f32_16x16x32_bf16(pf1[1], vv, o[1][dn], 0, 0, 0);
            }

            // one drain+barrier per tile: next tile's staging landed (vmcnt 0),
            // all waves done reading buf[cur] -> safe to overwrite at ktt+1
            __syncthreads();
        }

        // ---- epilogue: per-wave fp32 slab (aliases KV bufs; all waves past final barrier) ----
        float* Ot = (float*)smem + wave * (16 * 128);
        #pragma unroll
        for (int rb = 0; rb < 2; ++rb) {
            float inv[4];
            #pragma unroll
            for (int r = 0; r < 4; ++r) inv[r] = 1.f / l_i[rb][r];
            #pragma unroll
            for (int dn = 0; dn < 8; ++dn)
                #pragma unroll
                for (int r = 0; r < 4; ++r)
                    Ot[(quad * 4 + r) * 128 + dn * 16 + m16] = o[rb][dn][r] * inv[r];
            asm volatile("s_waitcnt lgkmcnt(0)" ::: "memory");
            float* og = out + (size_t)(b * S_ + qbase + rb * 64 + wave * 16) * (H_ * D_) + h * D_;
            #pragma unroll
            for (int i = 0; i < 8; ++i) {
                const int row = (lane >> 5) + i * 2;
                const int col = (lane & 31) * 4;
                *(float4*)(og + (size_t)row * (H_ * D_) + col) = *(const float4*)(Ot + row * 128 + col);
            }
            // LDS per-wave in-order: rb=1 ds_writes queue after rb=0 ds_reads (WAR safe)
        }
    }
}
#undef P_STRIDE

extern "C" void kernel_launch(void* const* d_in, const int* in_sizes, int n_in,
                              void* d_out, int out_size, void* d_ws, size_t ws_size,
                              hipStream_t stream) {
    const float* q = (const float*)d_in[0];
    const float* k = (const float*)d_in[1];
    const float* v = (const float*)d_in[2];
    float* out = (float*)d_out;

    unsigned short* kfb = (unsigned short*)d_ws;                                  // 8 MB
    unsigned short* vfb = (unsigned short*)d_ws + (size_t)B_ * KVH_ * S_ * D_;    // 8 MB

    prep_kernel<<<dim3(NT_, B_ * KVH_), dim3(256), 0, stream>>>(k, v, kfb, vfb);
    fa7_kernel<<<dim3(S_ / QB / 2, B_ * H_), dim3(256), 0, stream>>>(q, kfb, vfb, out);
}

// Round 2
// 264.309 us; speedup vs baseline: 1.4761x; 1.1154x over previous
//
#include <hip/hip_runtime.h>

#define B_    2
#define S_    2048
#define H_    32
#define KVH_  8
#define D_    128
#define QB    128
#define KB    64
#define NT_   (S_ / KB)
#define SCALE2 0.12751743f   // 128^-0.5 * log2(e): softmax runs in log2 domain

typedef short  short8 __attribute__((ext_vector_type(8)));
typedef float  f32x4  __attribute__((ext_vector_type(4)));

__device__ inline unsigned short f2bf(float f) {
    unsigned int u = __float_as_uint(f);
    u += 0x7fffu + ((u >> 16) & 1u);
    return (unsigned short)(u >> 16);
}
__device__ __forceinline__ float exp2_fast(float x) {   // v_exp_f32 = 2^x
    float r; asm("v_exp_f32 %0, %1" : "=v"(r) : "v"(x)); return r;
}

// ---- prepass: build MFMA-fragment-ordered bf16 K and V (verified round 5) ----
// kfb[(bkvh*NT+kt)*16 + (c*4+nt)][lane]  : K[key=kt*64+nt*16+m16][d=c*32+quad*8+j]
// vfb[(bkvh*NT+kt)*16 + (c2*8+dn)][lane] : V[key=kt*64+c2*32+quad*8+j][d=dn*16+m16]
__global__ void prep_kernel(const float* __restrict__ k, const float* __restrict__ v,
                            unsigned short* __restrict__ kfb,
                            unsigned short* __restrict__ vfb) {
    __shared__ unsigned short Kt[64][136];   // 272B row stride: 16B-aligned b128 reads
    __shared__ unsigned short Vt[64][132];   // 264B stride: transpose reads 4-way (was 8-way)
    const int t = threadIdx.x;
    const int kt = blockIdx.x, bkvh = blockIdx.y;
    const int b = bkvh >> 3, kvh = bkvh & 7;
    const size_t rs = KVH_ * D_;
    const float* ks = k + ((size_t)(b * S_ + kt * 64)) * rs + kvh * D_;
    const float* vs = v + ((size_t)(b * S_ + kt * 64)) * rs + kvh * D_;
    #pragma unroll
    for (int i = 0; i < 8; ++i) {
        const int row = (t >> 5) + i * 8;
        const int col = (t & 31) * 4;
        const float4 a = *(const float4*)(ks + (size_t)row * rs + col);
        const float4 c = *(const float4*)(vs + (size_t)row * rs + col);
        ushort4 wa, wc;
        wa.x = f2bf(a.x); wa.y = f2bf(a.y); wa.z = f2bf(a.z); wa.w = f2bf(a.w);
        wc.x = f2bf(c.x); wc.y = f2bf(c.y); wc.z = f2bf(c.z); wc.w = f2bf(c.w);
        *(ushort4*)&Kt[row][col] = wa;
        *(ushort4*)&Vt[row][col] = wc;
    }
    __syncthreads();
    const int lane = t & 63, m16 = lane & 15, quad = lane >> 4;
    unsigned short* kout = kfb + (size_t)(bkvh * NT_ + kt) * 16 * 512;
    unsigned short* vout = vfb + (size_t)(bkvh * NT_ + kt) * 16 * 512;
    #pragma unroll
    for (int i = 0; i < 4; ++i) {
        const int g = (t >> 6) * 4 + i;          // 0..15
        const int c = g >> 2, nt = g & 3;
        const short8 kk = *(const short8*)&Kt[nt * 16 + m16][c * 32 + quad * 8];
        *(short8*)(kout + g * 512 + lane * 8) = kk;
        const int c2 = g >> 3, dn = g & 7;
        short8 vv;
        #pragma unroll
        for (int j = 0; j < 8; ++j)
            vv[j] = (short)Vt[c2 * 32 + quad * 8 + j][dn * 16 + m16];
        *(short8*)(vout + g * 512 + lane * 8) = vv;
    }
}

// ---- fa8: 8 waves x 16 rows, dbuf LDS staging, swizzled Psh, deferred softmax ----
// LDS map (bytes): buf0 K[0,16K) V[16K,32K) | buf1 K[32K,48K) V[48K,64K)
//                  Psh [64K, 64K+16K): 128 rows x 64 shorts, XOR-block swizzle
//                  epilogue fp32 slab 8x[16][128] (64KB) aliases buf0+buf1
#define KV_TILE_B 16384
#define BUF_B     32768
#define PSH_OFF   65536
#define SMEM_B    (PSH_OFF + 128 * 64 * 2)   // 81920 B = 80KB -> exactly 2 blocks/CU

__device__ __forceinline__ void gld16(const void* g, void* l) {
    __builtin_amdgcn_global_load_lds(
        (const __attribute__((address_space(1))) unsigned int*)g,
        (__attribute__((address_space(3))) unsigned int*)l, 16, 0, 0);
}

__global__ __launch_bounds__(512, 4) void fa8_kernel(
    const float* __restrict__ q, const unsigned short* __restrict__ kfb,
    const unsigned short* __restrict__ vfb, float* __restrict__ out) {

    __shared__ __align__(16) char smem[SMEM_B];
    unsigned short* Psh = (unsigned short*)(smem + PSH_OFF);

    const int t    = threadIdx.x;
    const int wave = t >> 6;          // 0..7, owns 16 q-rows
    const int lane = t & 63;
    const int m16  = lane & 15;
    const int quad = lane >> 4;
    const int hi3  = m16 >> 3;        // swizzle helpers
    const int off3 = m16 & 7;

    const int bh  = blockIdx.y;
    const int b   = bh >> 5;
    const int h   = bh & 31;
    const int kvh = h >> 2;

    const char* kB = (const char*)kfb + (size_t)(b * KVH_ + kvh) * NT_ * KV_TILE_B;
    const char* vB = (const char*)vfb + (size_t)(b * KVH_ + kvh) * NT_ * KV_TILE_B;

    // causal pairing: qtile (15-bx) then (bx) -> every block does exactly 34 k-tile iters
    for (int half = 0; half < 2; ++half) {
        const int qtile = half ? (int)blockIdx.x : (S_ / QB - 1 - (int)blockIdx.x);
        const int qbase = qtile * QB;
        const int ktmax = 2 * qtile + 1;

        if (half) __syncthreads();   // epilogue slab reads of half 0 done before restaging buf0

        // ---- stage tile 0 -> buf0 (512 thr x 16B x 2 rounds each for K,V) ----
        #pragma unroll
        for (int r = 0; r < 2; ++r) {
            gld16(kB + r * 8192 + t * 16, smem + r * 8192 + t * 16);
            gld16(vB + r * 8192 + t * 16, smem + KV_TILE_B + r * 8192 + t * 16);
        }

        // ---- Q A-fragments: rows qbase + wave*16 + m16 (hides under staging drain) ----
        short8 qf[4];
        {
            const float* qp = q + (size_t)(b * S_ + qbase + wave * 16 + m16) * (H_ * D_) + h * D_;
            #pragma unroll
            for (int c = 0; c < 4; ++c) {
                const float4 x0 = *(const float4*)(qp + c * 32 + quad * 8);
                const float4 x1 = *(const float4*)(qp + c * 32 + quad * 8 + 4);
                short8 f;
                f[0] = (short)f2bf(x0.x); f[1] = (short)f2bf(x0.y);
                f[2] = (short)f2bf(x0.z); f[3] = (short)f2bf(x0.w);
                f[4] = (short)f2bf(x1.x); f[5] = (short)f2bf(x1.y);
                f[6] = (short)f2bf(x1.z); f[7] = (short)f2bf(x1.w);
                qf[c] = f;
            }
        }

        f32x4 o[8];
        #pragma unroll
        for (int i = 0; i < 8; ++i) o[i] = (f32x4){0.f, 0.f, 0.f, 0.f};
        float m_i[4], l_i[4];
        #pragma unroll
        for (int r = 0; r < 4; ++r) { m_i[r] = -INFINITY; l_i[r] = 0.f; }

        __syncthreads();   // drains vmcnt(0): tile 0 staged and visible

        for (int ktt = 0; ktt <= ktmax; ++ktt) {
            const int kb  = ktt * KB;
            const int cur = ktt & 1;

            // ---- issue next tile's staging; flies under this tile's compute ----
            if (ktt < ktmax) {
                char* dst = smem + (cur ^ 1) * BUF_B + t * 16;
                const char* ks = kB + (size_t)(ktt + 1) * KV_TILE_B + t * 16;
                const char* vs = vB + (size_t)(ktt + 1) * KV_TILE_B + t * 16;
                #pragma unroll
                for (int r = 0; r < 2; ++r) {
                    gld16(ks + r * 8192, dst + r * 8192);
                    gld16(vs + r * 8192, dst + KV_TILE_B + r * 8192);
                }
            }
            const unsigned short* Kl = (const unsigned short*)(smem + cur * BUF_B);
            const unsigned short* Vl = Kl + KV_TILE_B / 2;

            // ---- S = Q K^T (16 MFMA), K frags from LDS ----
            f32x4 sa[4];
            #pragma unroll
            for (int nt = 0; nt < 4; ++nt) sa[nt] = (f32x4){0.f, 0.f, 0.f, 0.f};
            #pragma unroll
            for (int c = 0; c < 4; ++c) {
                short8 kf[4];
                #pragma unroll
                for (int nt = 0; nt < 4; ++nt)
                    kf[nt] = *(const short8*)(Kl + (c * 4 + nt) * 512 + lane * 8);
                #pragma unroll
                for (int nt = 0; nt < 4; ++nt)
                    sa[nt] = __builtin_amdgcn_mfma_f32_16x16x32_bf16(qf[c], kf[nt], sa[nt], 0, 0, 0);
            }

            // ---- mask + online softmax (log2 domain, defer-max, per-lane l) ----
            const bool dodiag = (ktt >= 2 * qtile);
            float p[4][4];
            #pragma unroll
            for (int nt = 0; nt < 4; ++nt) {
                #pragma unroll
                for (int r = 0; r < 4; ++r) {
                    float sv = sa[nt][r] * SCALE2;
                    if (dodiag) {
                        const int rowg = qbase + wave * 16 + quad * 4 + r;
                        const int colg = kb + nt * 16 + m16;
                        if (colg > rowg) sv = -INFINITY;
                    }
                    p[nt][r] = sv;
                }
            }
            float mv[4];
            #pragma unroll
            for (int r = 0; r < 4; ++r) {
                float m0 = fmaxf(fmaxf(p[0][r], p[1][r]), fmaxf(p[2][r], p[3][r]));
                m0 = fmaxf(m0, __shfl_xor(m0, 1));
                m0 = fmaxf(m0, __shfl_xor(m0, 2));
                m0 = fmaxf(m0, __shfl_xor(m0, 4));
                m0 = fmaxf(m0, __shfl_xor(m0, 8));
                mv[r] = m0;
            }
            // defer-max THR=0: rescale only if some row's max actually grew (exact math)
            const float dmax = fmaxf(fmaxf(mv[0] - m_i[0], mv[1] - m_i[1]),
                                     fmaxf(mv[2] - m_i[2], mv[3] - m_i[3]));
            if (__any(dmax > 0.f)) {
                #pragma unroll
                for (int r = 0; r < 4; ++r) {
                    const float mnew = fmaxf(m_i[r], mv[r]);
                    const float al = exp2_fast(m_i[r] - mnew);
                    m_i[r] = mnew;
                    l_i[r] *= al;
                    #pragma unroll
                    for (int dn = 0; dn < 8; ++dn) o[dn][r] *= al;
                }
            }
            // exp + per-lane partial row-sum (cross-lane reduce deferred to epilogue)
            #pragma unroll
            for (int nt = 0; nt < 4; ++nt) {
                #pragma unroll
                for (int r = 0; r < 4; ++r) {
                    const float e = exp2_fast(p[nt][r] - m_i[r]);
                    l_i[r] += e;
                    // Psh write, XOR-block swizzle: row=wave*16+quad*4+r, col=nt*16+m16
                    const int prow = wave * 16 + quad * 4 + r;
                    const int blk  = (nt * 2 + hi3) ^ (prow & 7);
                    Psh[prow * 64 + blk * 8 + off3] = f2bf(e);
                }
            }
            // same-wave LDS RAW: drain P writes, then read A-fragments (wave-private rows)
            asm volatile("s_waitcnt lgkmcnt(0)" ::: "memory");
            short8 pf[2];
            {
                const int rrow = wave * 16 + m16;
                pf[0] = *(const short8*)&Psh[rrow * 64 + ((quad ^ off3) << 3)];
                pf[1] = *(const short8*)&Psh[rrow * 64 + (((4 + quad) ^ off3) << 3)];
            }

            // ---- O += P V (16 MFMA), V frags from LDS ----
            #pragma unroll
            for (int dn = 0; dn < 8; ++dn) {
                const short8 vv = *(const short8*)(Vl + dn * 512 + lane * 8);
                o[dn] = __builtin_amdgcn_mfma_f32_16x16x32_bf16(pf[0], vv, o[dn], 0, 0, 0);
            }
            #pragma unroll
            for (int dn = 0; dn < 8; ++dn) {
                const short8 vv = *(const short8*)(Vl + (8 + dn) * 512 + lane * 8);
                o[dn] = __builtin_amdgcn_mfma_f32_16x16x32_bf16(pf[1], vv, o[dn], 0, 0, 0);
            }

            // one drain+barrier per tile: next tile staged (vmcnt 0), buf[cur] free
            __syncthreads();
        }

        // ---- epilogue: deferred l reduce, per-wave fp32 slab (aliases KV bufs) ----
        float inv[4];
        #pragma unroll
        for (int r = 0; r < 4; ++r) {
            float rs = l_i[r];
            rs += __shfl_xor(rs, 1);
            rs += __shfl_xor(rs, 2);
            rs += __shfl_xor(rs, 4);
            rs += __shfl_xor(rs, 8);
            inv[r] = 1.f / rs;
        }
        float* Ot = (float*)smem + wave * (16 * 128);
        #pragma unroll
        for (int dn = 0; dn < 8; ++dn)
            #pragma unroll
            for (int r = 0; r < 4; ++r)
                Ot[(quad * 4 + r) * 128 + dn * 16 + m16] = o[dn][r] * inv[r];
        asm volatile("s_waitcnt lgkmcnt(0)" ::: "memory");
        float* og = out + (size_t)(b * S_ + qbase + wave * 16) * (H_ * D_) + h * D_;
        #pragma unroll
        for (int i = 0; i < 8; ++i) {
            const int row = (lane >> 5) + i * 2;
            const int col = (lane & 31) * 4;
            *(float4*)(og + (size_t)row * (H_ * D_) + col) = *(const float4*)(Ot + row * 128 + col);
        }
    }
}

extern "C" void kernel_launch(void* const* d_in, const int* in_sizes, int n_in,
                              void* d_out, int out_size, void* d_ws, size_t ws_size,
                              hipStream_t stream) {
    const float* q = (const float*)d_in[0];
    const float* k = (const float*)d_in[1];
    const float* v = (const float*)d_in[2];
    float* out = (float*)d_out;

    unsigned short* kfb = (unsigned short*)d_ws;                                  // 8 MB
    unsigned short* vfb = (unsigned short*)d_ws + (size_t)B_ * KVH_ * S_ * D_;    // 8 MB

    prep_kernel<<<dim3(NT_, B_ * KVH_), dim3(256), 0, stream>>>(k, v, kfb, vfb);
    fa8_kernel<<<dim3(S_ / QB / 2, B_ * H_), dim3(512), 0, stream>>>(q, kfb, vfb, out);
}

// Round 3
// 225.924 us; speedup vs baseline: 1.7269x; 1.1699x over previous
//
#include <hip/hip_runtime.h>

#define B_    2
#define S_    2048
#define H_    32
#define KVH_  8
#define D_    128
#define QB    128
#define KB    64
#define NT_   (S_ / KB)
#define SCALE2 0.12751743f   // 128^-0.5 * log2(e): softmax in log2 domain (folded into Q)
#define THR2  8.0f           // defer-max threshold (log2): P bounded by 2^8, bf16-safe

typedef short  short8 __attribute__((ext_vector_type(8)));
typedef float  f32x4  __attribute__((ext_vector_type(4)));

__device__ inline unsigned short f2bf(float f) {
    unsigned int u = __float_as_uint(f);
    u += 0x7fffu + ((u >> 16) & 1u);
    return (unsigned short)(u >> 16);
}
__device__ __forceinline__ float exp2_fast(float x) {   // v_exp_f32 = 2^x
    float r; asm("v_exp_f32 %0, %1" : "=v"(r) : "v"(x)); return r;
}
__device__ __forceinline__ unsigned int cvt_pk_bf16(float lo, float hi) {
    unsigned int r;
    asm("v_cvt_pk_bf16_f32 %0, %1, %2" : "=v"(r) : "v"(lo), "v"(hi));
    return r;
}

// ---- prepass: build MFMA-fragment-ordered bf16 K and V (verified) ----
// kfb[(bkvh*NT+kt)*16 + (c*4+nt)][lane]  : K[key=kt*64+nt*16+m16][d=c*32+quad*8+j]
// vfb[(bkvh*NT+kt)*16 + (c2*8+dn)][lane] : V[key=kt*64+c2*32+quad*8+j][d=dn*16+m16]
__global__ void prep_kernel(const float* __restrict__ k, const float* __restrict__ v,
                            unsigned short* __restrict__ kfb,
                            unsigned short* __restrict__ vfb) {
    __shared__ unsigned short Kt[64][136];
    __shared__ unsigned short Vt[64][132];
    const int t = threadIdx.x;
    const int kt = blockIdx.x, bkvh = blockIdx.y;
    const int b = bkvh >> 3, kvh = bkvh & 7;
    const size_t rs = KVH_ * D_;
    const float* ks = k + ((size_t)(b * S_ + kt * 64)) * rs + kvh * D_;
    const float* vs = v + ((size_t)(b * S_ + kt * 64)) * rs + kvh * D_;
    #pragma unroll
    for (int i = 0; i < 8; ++i) {
        const int row = (t >> 5) + i * 8;
        const int col = (t & 31) * 4;
        const float4 a = *(const float4*)(ks + (size_t)row * rs + col);
        const float4 c = *(const float4*)(vs + (size_t)row * rs + col);
        ushort4 wa, wc;
        wa.x = f2bf(a.x); wa.y = f2bf(a.y); wa.z = f2bf(a.z); wa.w = f2bf(a.w);
        wc.x = f2bf(c.x); wc.y = f2bf(c.y); wc.z = f2bf(c.z); wc.w = f2bf(c.w);
        *(ushort4*)&Kt[row][col] = wa;
        *(ushort4*)&Vt[row][col] = wc;
    }
    __syncthreads();
    const int lane = t & 63, m16 = lane & 15, quad = lane >> 4;
    unsigned short* kout = kfb + (size_t)(bkvh * NT_ + kt) * 16 * 512;
    unsigned short* vout = vfb + (size_t)(bkvh * NT_ + kt) * 16 * 512;
    #pragma unroll
    for (int i = 0; i < 4; ++i) {
        const int g = (t >> 6) * 4 + i;          // 0..15
        const int c = g >> 2, nt = g & 3;
        const short8 kk = *(const short8*)&Kt[nt * 16 + m16][c * 32 + quad * 8];
        *(short8*)(kout + g * 512 + lane * 8) = kk;
        const int c2 = g >> 3, dn = g & 7;
        short8 vv;
        #pragma unroll
        for (int j = 0; j < 8; ++j)
            vv[j] = (short)Vt[c2 * 32 + quad * 8 + j][dn * 16 + m16];
        *(short8*)(vout + g * 512 + lane * 8) = vv;
    }
}

// ---- fa9: swapped QK^T -> per-lane softmax; packed b64 P writes; defer-max ----
// sa = mfma(K,Q): lane holds S[key = nt*16+quad*4+r][q = m16] -> row-softmax is lane-local.
// LDS map: buf0 K[0,16K) V[16K,32K) | buf1 [32K,64K) | Psh [64K,80K) 128x64 shorts swizzled
#define KV_TILE_B 16384
#define BUF_B     32768
#define PSH_OFF   65536
#define SMEM_B    (PSH_OFF + 128 * 64 * 2)   // 80 KB -> exactly 2 blocks/CU

__device__ __forceinline__ void gld16(const void* g, void* l) {
    __builtin_amdgcn_global_load_lds(
        (const __attribute__((address_space(1))) unsigned int*)g,
        (__attribute__((address_space(3))) unsigned int*)l, 16, 0, 0);
}

__global__ __launch_bounds__(512, 4) void fa9_kernel(
    const float* __restrict__ q, const unsigned short* __restrict__ kfb,
    const unsigned short* __restrict__ vfb, float* __restrict__ out) {

    __shared__ __align__(16) char smem[SMEM_B];
    unsigned short* Psh = (unsigned short*)(smem + PSH_OFF);

    const int t    = threadIdx.x;
    const int wave = t >> 6;          // 0..7, owns 16 q-rows
    const int lane = t & 63;
    const int m16  = lane & 15;       // = this lane's q-row (swapped layout)
    const int quad = lane >> 4;

    const int bh  = blockIdx.y;
    const int b   = bh >> 5;
    const int h   = bh & 31;
    const int kvh = h >> 2;

    const char* kB = (const char*)kfb + (size_t)(b * KVH_ + kvh) * NT_ * KV_TILE_B;
    const char* vB = (const char*)vfb + (size_t)(b * KVH_ + kvh) * NT_ * KV_TILE_B;

    // Psh addressing (hoisted): write value(q=m16, col=nt*16+quad*4+r) packed 4-r b64;
    // swizzle blk = (col>>3) ^ (m16&7) — same involution on read.
    const int prow_base = (wave * 16 + m16) * 64;
    unsigned short* pw[4];
    #pragma unroll
    for (int nt = 0; nt < 4; ++nt)
        pw[nt] = Psh + prow_base + (((nt * 2 + (quad >> 1)) ^ (m16 & 7)) << 3) + (quad & 1) * 4;
    const unsigned short* pr0 = Psh + prow_base + (((quad)     ^ (m16 & 7)) << 3);
    const unsigned short* pr1 = Psh + prow_base + (((4 + quad) ^ (m16 & 7)) << 3);

    // causal pairing: qtile (15-bx) then (bx) -> every block does exactly 34 k-tile iters
    for (int half = 0; half < 2; ++half) {
        const int qtile = half ? (int)blockIdx.x : (S_ / QB - 1 - (int)blockIdx.x);
        const int qbase = qtile * QB;
        const int ktmax = 2 * qtile + 1;
        const int qrow  = qbase + wave * 16 + m16;   // this lane's global q-row

        if (half) __syncthreads();   // epilogue slab reads of half 0 done before restaging buf0

        // ---- stage tile 0 -> buf0 ----
        #pragma unroll
        for (int r = 0; r < 2; ++r) {
            gld16(kB + r * 8192 + t * 16, smem + r * 8192 + t * 16);
            gld16(vB + r * 8192 + t * 16, smem + KV_TILE_B + r * 8192 + t * 16);
        }

        // ---- Q A-fragments, pre-scaled by SCALE2 (kills 16 muls/iter) ----
        short8 qf[4];
        {
            const float* qp = q + (size_t)(b * S_ + qrow) * (H_ * D_) + h * D_;
            #pragma unroll
            for (int c = 0; c < 4; ++c) {
                const float4 x0 = *(const float4*)(qp + c * 32 + quad * 8);
                const float4 x1 = *(const float4*)(qp + c * 32 + quad * 8 + 4);
                short8 f;
                f[0] = (short)f2bf(x0.x * SCALE2); f[1] = (short)f2bf(x0.y * SCALE2);
                f[2] = (short)f2bf(x0.z * SCALE2); f[3] = (short)f2bf(x0.w * SCALE2);
                f[4] = (short)f2bf(x1.x * SCALE2); f[5] = (short)f2bf(x1.y * SCALE2);
                f[6] = (short)f2bf(x1.z * SCALE2); f[7] = (short)f2bf(x1.w * SCALE2);
                qf[c] = f;
            }
        }

        f32x4 o[8];
        #pragma unroll
        for (int i = 0; i < 8; ++i) o[i] = (f32x4){0.f, 0.f, 0.f, 0.f};
        float m_q = -INFINITY, l_q = 0.f;   // per-lane: row q = m16, keys of own quad-slice

        __syncthreads();   // tile 0 staged and visible

        for (int ktt = 0; ktt <= ktmax; ++ktt) {
            const int kb  = ktt * KB;
            const int cur = ktt & 1;

            if (ktt < ktmax) {
                char* dst = smem + (cur ^ 1) * BUF_B + t * 16;
                const char* ks = kB + (size_t)(ktt + 1) * KV_TILE_B + t * 16;
                const char* vs = vB + (size_t)(ktt + 1) * KV_TILE_B + t * 16;
                #pragma unroll
                for (int r = 0; r < 2; ++r) {
                    gld16(ks + r * 8192, dst + r * 8192);
                    gld16(vs + r * 8192, dst + KV_TILE_B + r * 8192);
                }
            }
            const unsigned short* Kl = (const unsigned short*)(smem + cur * BUF_B);
            const unsigned short* Vl = Kl + KV_TILE_B / 2;

            // ---- S^T = K Q^T (swapped): sa[nt] = S[key=nt*16+quad*4+r][q=m16] ----
            f32x4 sa[4];
            #pragma unroll
            for (int nt = 0; nt < 4; ++nt) sa[nt] = (f32x4){0.f, 0.f, 0.f, 0.f};
            #pragma unroll
            for (int c = 0; c < 4; ++c) {
                short8 kf[4];
                #pragma unroll
                for (int nt = 0; nt < 4; ++nt)
                    kf[nt] = *(const short8*)(Kl + (c * 4 + nt) * 512 + lane * 8);
                #pragma unroll
                for (int nt = 0; nt < 4; ++nt)
                    sa[nt] = __builtin_amdgcn_mfma_f32_16x16x32_bf16(kf[nt], qf[c], sa[nt], 0, 0, 0);
            }

            // ---- mask (lane-local row) ----
            const bool dodiag = (ktt >= 2 * qtile);
            float p[4][4];
            #pragma unroll
            for (int nt = 0; nt < 4; ++nt) {
                #pragma unroll
                for (int r = 0; r < 4; ++r) {
                    float sv = sa[nt][r];
                    if (dodiag) {
                        const int keyg = kb + nt * 16 + quad * 4 + r;
                        if (keyg > qrow) sv = -INFINITY;
                    }
                    p[nt][r] = sv;
                }
            }
            // ---- per-lane max over 16 keys + 2 cross-quad swaps ----
            float mv;
            {
                float t0 = fmaxf(fmaxf(p[0][0], p[0][1]), fmaxf(p[0][2], p[0][3]));
                float t1 = fmaxf(fmaxf(p[1][0], p[1][1]), fmaxf(p[1][2], p[1][3]));
                float t2 = fmaxf(fmaxf(p[2][0], p[2][1]), fmaxf(p[2][2], p[2][3]));
                float t3 = fmaxf(fmaxf(p[3][0], p[3][1]), fmaxf(p[3][2], p[3][3]));
                mv = fmaxf(fmaxf(t0, t1), fmaxf(t2, t3));
                mv = fmaxf(mv, __shfl_xor(mv, 16));
                mv = fmaxf(mv, __shfl_xor(mv, 32));
            }
            // ---- defer-max (THR2 log2-units): rescale only on big max growth ----
            if (__any(mv - m_q > THR2)) {
                const float mnew = fmaxf(m_q, mv);
                const float al = exp2_fast(m_q - mnew);   // m_q=-inf -> al=0 (o is 0 anyway)
                m_q = mnew;
                l_q *= al;
                float alo[4];
                #pragma unroll
                for (int r = 0; r < 4; ++r)
                    alo[r] = __shfl(al, quad * 20 + r);   // alpha of o-row quad*4+r (same quad grp)
                #pragma unroll
                for (int dn = 0; dn < 8; ++dn)
                    #pragma unroll
                    for (int r = 0; r < 4; ++r) o[dn][r] *= alo[r];
            }
            // ---- exp + lane-local l + packed bf16 P write (2 cvt_pk + 1 b64 per nt) ----
            #pragma unroll
            for (int nt = 0; nt < 4; ++nt) {
                const float e0 = exp2_fast(p[nt][0] - m_q);
                const float e1 = exp2_fast(p[nt][1] - m_q);
                const float e2 = exp2_fast(p[nt][2] - m_q);
                const float e3 = exp2_fast(p[nt][3] - m_q);
                l_q += (e0 + e1) + (e2 + e3);
                uint2 w;
                w.x = cvt_pk_bf16(e0, e1);
                w.y = cvt_pk_bf16(e2, e3);
                *(uint2*)pw[nt] = w;
            }
            // same-wave LDS RAW: drain P writes, read PV A-fragments (wave-private rows)
            asm volatile("s_waitcnt lgkmcnt(0)" ::: "memory");
            short8 pf[2];
            pf[0] = *(const short8*)pr0;
            pf[1] = *(const short8*)pr1;

            // ---- O += P V (V frags from LDS; o layout unchanged: row q=quad*4+r, col d=m16) ----
            #pragma unroll
            for (int dn = 0; dn < 8; ++dn) {
                const short8 vv = *(const short8*)(Vl + dn * 512 + lane * 8);
                o[dn] = __builtin_amdgcn_mfma_f32_16x16x32_bf16(pf[0], vv, o[dn], 0, 0, 0);
            }
            #pragma unroll
            for (int dn = 0; dn < 8; ++dn) {
                const short8 vv = *(const short8*)(Vl + (8 + dn) * 512 + lane * 8);
                o[dn] = __builtin_amdgcn_mfma_f32_16x16x32_bf16(pf[1], vv, o[dn], 0, 0, 0);
            }

            __syncthreads();   // next tile staged (vmcnt 0), buf[cur] free
        }

        // ---- epilogue: cross-quad l reduce at own row, redistribute inv to o-rows ----
        float ls = l_q;
        ls += __shfl_xor(ls, 16);
        ls += __shfl_xor(ls, 32);
        const float inv_q = 1.f / ls;
        float inv[4];
        #pragma unroll
        for (int r = 0; r < 4; ++r)
            inv[r] = __shfl(inv_q, quad * 20 + r);

        float* Ot = (float*)smem + wave * (16 * 128);
        #pragma unroll
        for (int dn = 0; dn < 8; ++dn)
            #pragma unroll
            for (int r = 0; r < 4; ++r)
                Ot[(quad * 4 + r) * 128 + dn * 16 + m16] = o[dn][r] * inv[r];
        asm volatile("s_waitcnt lgkmcnt(0)" ::: "memory");
        float* og = out + (size_t)(b * S_ + qbase + wave * 16) * (H_ * D_) + h * D_;
        #pragma unroll
        for (int i = 0; i < 8; ++i) {
            const int row = (lane >> 5) + i * 2;
            const int col = (lane & 31) * 4;
            *(float4*)(og + (size_t)row * (H_ * D_) + col) = *(const float4*)(Ot + row * 128 + col);
        }
    }
}

extern "C" void kernel_launch(void* const* d_in, const int* in_sizes, int n_in,
                              void* d_out, int out_size, void* d_ws, size_t ws_size,
                              hipStream_t stream) {
    const float* q = (const float*)d_in[0];
    const float* k = (const float*)d_in[1];
    const float* v = (const float*)d_in[2];
    float* out = (float*)d_out;

    unsigned short* kfb = (unsigned short*)d_ws;                                  // 8 MB
    unsigned short* vfb = (unsigned short*)d_ws + (size_t)B_ * KVH_ * S_ * D_;    // 8 MB

    prep_kernel<<<dim3(NT_, B_ * KVH_), dim3(256), 0, stream>>>(k, v, kfb, vfb);
    fa9_kernel<<<dim3(S_ / QB / 2, B_ * H_), dim3(512), 0, stream>>>(q, kfb, vfb, out);
}